// Round 1
// baseline (432.231 us; speedup 1.0000x reference)
//
#include <hip/hip_runtime.h>

// Problem constants (from setup_inputs): x [B=2, C=3, D=128, H=160, W=160] fp32, num_steps=6
#define BB 2
#define DD 128
#define HH 160
#define WW 160
constexpr int S  = DD * HH * WW;   // per-channel plane elements = 3,276,800
constexpr int NV = BB * S;         // voxels across batches       = 6,553,600

// One squaring step: vout(p) = s*vin(p) + s*vin(round(p + s*vin(p)))
// 'scale' is 1/64 on the first pass (fuses the initial scaling), 1 afterwards.
__global__ __launch_bounds__(256) void warp_step(const float* __restrict__ vin,
                                                 float* __restrict__ vout,
                                                 float scale) {
    int idx = blockIdx.x * 256 + threadIdx.x;
    if (idx >= NV) return;
    int b = idx / S;
    int p = idx - b * S;
    int w = p % WW;
    int t = p / WW;
    int h = t % HH;
    int d = t / HH;

    int base = b * 3 * S + p;
    float f0 = vin[base] * scale;           // d-displacement
    float f1 = vin[base + S] * scale;       // h-displacement
    float f2 = vin[base + 2 * S] * scale;   // w-displacement

    // round-half-to-even (matches jnp.round), then clamp per-dim
    int id = (int)fminf(fmaxf(rintf((float)d + f0), 0.0f), (float)(DD - 1));
    int ih = (int)fminf(fmaxf(rintf((float)h + f1), 0.0f), (float)(HH - 1));
    int iw = (int)fminf(fmaxf(rintf((float)w + f2), 0.0f), (float)(WW - 1));

    int q = b * 3 * S + ((id * HH + ih) * WW + iw);
    float g0 = vin[q] * scale;
    float g1 = vin[q + S] * scale;
    float g2 = vin[q + 2 * S] * scale;

    vout[base]         = f0 + g0;
    vout[base + S]     = f1 + g1;
    vout[base + 2 * S] = f2 + g2;
}

extern "C" void kernel_launch(void* const* d_in, const int* in_sizes, int n_in,
                              void* d_out, int out_size, void* d_ws, size_t ws_size,
                              hipStream_t stream) {
    const float* x = (const float*)d_in[0];
    float* out = (float*)d_out;
    float* ws  = (float*)d_ws;   // needs NV*3*4 = 78,643,200 bytes

    const int grid = (NV + 255) / 256;

    // num_steps = 6 (fixed by setup_inputs). Ping-pong so pass 6 lands in d_out.
    warp_step<<<grid, 256, 0, stream>>>(x,   ws,  1.0f / 64.0f);  // step 1 (scale fused)
    warp_step<<<grid, 256, 0, stream>>>(ws,  out, 1.0f);          // step 2
    warp_step<<<grid, 256, 0, stream>>>(out, ws,  1.0f);          // step 3
    warp_step<<<grid, 256, 0, stream>>>(ws,  out, 1.0f);          // step 4
    warp_step<<<grid, 256, 0, stream>>>(out, ws,  1.0f);          // step 5
    warp_step<<<grid, 256, 0, stream>>>(ws,  out, 1.0f);          // step 6
}

// Round 2
// 420.799 us; speedup vs baseline: 1.0272x; 1.0272x over previous
//
#include <hip/hip_runtime.h>

// x: [B=2, C=3, D=128, H=160, W=160] fp32, num_steps=6
#define BB 2
#define DD 128
#define HH 160
#define WW 160
constexpr int S   = DD * HH * WW;   // voxels per batch   = 3,276,800
constexpr int PL  = HH * WW;        // plane (h*w)        = 25,600
constexpr int NBX = PL / 256;       // 100 blocks per plane

__device__ __forceinline__ int warp_index(int d, int h, int w,
                                          float f0, float f1, float f2) {
    // round-half-to-even (jnp.round == rintf), clamp per-dim
    int id = (int)fminf(fmaxf(rintf((float)d + f0), 0.0f), (float)(DD - 1));
    int ih = (int)fminf(fmaxf(rintf((float)h + f1), 0.0f), (float)(HH - 1));
    int iw = (int)fminf(fmaxf(rintf((float)w + f2), 0.0f), (float)(WW - 1));
    return (id * HH + ih) * WW + iw;
}

// Pass 1: read SoA x (scaled by 1/64), write AoS (stride VS)
template <int VS>
__global__ __launch_bounds__(256) void step_first(const float* __restrict__ x,
                                                  float* __restrict__ vout) {
    const float scale = 1.0f / 64.0f;
    int ip = blockIdx.x * 256 + threadIdx.x;    // [0, PL)
    int w = ip % WW, h = ip / WW;
    int d = blockIdx.y, b = blockIdx.z;
    int p = d * PL + ip;
    int soa = b * 3 * S + p;
    float f0 = x[soa] * scale, f1 = x[soa + S] * scale, f2 = x[soa + 2 * S] * scale;
    int q  = warp_index(d, h, w, f0, f1, f2);
    int qs = b * 3 * S + q;
    float g0 = x[qs] * scale, g1 = x[qs + S] * scale, g2 = x[qs + 2 * S] * scale;
    int ob = (b * S + p) * VS;
    if constexpr (VS == 4) {
        *(float4*)(vout + ob) = make_float4(f0 + g0, f1 + g1, f2 + g2, 0.0f);
    } else {
        vout[ob] = f0 + g0; vout[ob + 1] = f1 + g1; vout[ob + 2] = f2 + g2;
    }
}

// Passes 2..5: AoS -> AoS
template <int VS>
__global__ __launch_bounds__(256) void step_mid(const float* __restrict__ vin,
                                                float* __restrict__ vout) {
    int ip = blockIdx.x * 256 + threadIdx.x;
    int w = ip % WW, h = ip / WW;
    int d = blockIdx.y, b = blockIdx.z;
    int p = d * PL + ip;
    int ib = (b * S + p) * VS;
    float f0, f1, f2;
    if constexpr (VS == 4) {
        float4 t = *(const float4*)(vin + ib);
        f0 = t.x; f1 = t.y; f2 = t.z;
    } else {
        f0 = vin[ib]; f1 = vin[ib + 1]; f2 = vin[ib + 2];
    }
    int q  = warp_index(d, h, w, f0, f1, f2);
    int qb = (b * S + q) * VS;
    float g0, g1, g2;
    if constexpr (VS == 4) {
        float4 t = *(const float4*)(vin + qb);
        g0 = t.x; g1 = t.y; g2 = t.z;
    } else {
        g0 = vin[qb]; g1 = vin[qb + 1]; g2 = vin[qb + 2];
    }
    if constexpr (VS == 4) {
        *(float4*)(vout + ib) = make_float4(f0 + g0, f1 + g1, f2 + g2, 0.0f);
    } else {
        vout[ib] = f0 + g0; vout[ib + 1] = f1 + g1; vout[ib + 2] = f2 + g2;
    }
}

// Pass 6: AoS -> SoA d_out
template <int VS>
__global__ __launch_bounds__(256) void step_last(const float* __restrict__ vin,
                                                 float* __restrict__ vout) {
    int ip = blockIdx.x * 256 + threadIdx.x;
    int w = ip % WW, h = ip / WW;
    int d = blockIdx.y, b = blockIdx.z;
    int p = d * PL + ip;
    int ib = (b * S + p) * VS;
    float f0, f1, f2;
    if constexpr (VS == 4) {
        float4 t = *(const float4*)(vin + ib);
        f0 = t.x; f1 = t.y; f2 = t.z;
    } else {
        f0 = vin[ib]; f1 = vin[ib + 1]; f2 = vin[ib + 2];
    }
    int q  = warp_index(d, h, w, f0, f1, f2);
    int qb = (b * S + q) * VS;
    float g0, g1, g2;
    if constexpr (VS == 4) {
        float4 t = *(const float4*)(vin + qb);
        g0 = t.x; g1 = t.y; g2 = t.z;
    } else {
        g0 = vin[qb]; g1 = vin[qb + 1]; g2 = vin[qb + 2];
    }
    int ob = b * 3 * S + p;
    vout[ob]         = f0 + g0;
    vout[ob + S]     = f1 + g1;
    vout[ob + 2 * S] = f2 + g2;
}

extern "C" void kernel_launch(void* const* d_in, const int* in_sizes, int n_in,
                              void* d_out, int out_size, void* d_ws, size_t ws_size,
                              hipStream_t stream) {
    const float* x = (const float*)d_in[0];
    float* out = (float*)d_out;
    float* ws  = (float*)d_ws;

    dim3 grid(NBX, DD, BB);
    const size_t buf4 = (size_t)BB * S * 4;              // floats per padded AoS buffer
    const size_t need4 = 2 * buf4 * sizeof(float);       // 209,715,200 bytes

    if (ws_size >= need4) {
        // float4-padded AoS, double-buffered inside ws (aligned 16B gathers, 1 line each)
        float* A = ws;
        float* B = ws + buf4;
        step_first<4><<<grid, 256, 0, stream>>>(x, A);   // step 1 (scale fused)
        step_mid  <4><<<grid, 256, 0, stream>>>(A, B);   // step 2
        step_mid  <4><<<grid, 256, 0, stream>>>(B, A);   // step 3
        step_mid  <4><<<grid, 256, 0, stream>>>(A, B);   // step 4
        step_mid  <4><<<grid, 256, 0, stream>>>(B, A);   // step 5
        step_last <4><<<grid, 256, 0, stream>>>(A, out); // step 6 -> SoA
    } else {
        // tight 12B AoS, ping-pong ws <-> d_out (both hold exactly NV*3 floats)
        step_first<3><<<grid, 256, 0, stream>>>(x, ws);
        step_mid  <3><<<grid, 256, 0, stream>>>(ws, out);
        step_mid  <3><<<grid, 256, 0, stream>>>(out, ws);
        step_mid  <3><<<grid, 256, 0, stream>>>(ws, out);
        step_mid  <3><<<grid, 256, 0, stream>>>(out, ws);
        step_last <3><<<grid, 256, 0, stream>>>(ws, out);
    }
}

// Round 3
// 267.674 us; speedup vs baseline: 1.6148x; 1.5721x over previous
//
#include <hip/hip_runtime.h>

// x: [B=2, C=3, D=128, H=160, W=160] fp32, num_steps=6
#define BB 2
#define DD 128
#define HH 160
#define WW 160
constexpr int S   = DD * HH * WW;   // voxels per batch   = 3,276,800
constexpr int PL  = HH * WW;        // plane (h*w)        = 25,600
constexpr int VPB = 512;            // voxels per block (2 per thread)
constexpr int BPP = PL / VPB;       // 50 blocks per plane
constexpr int NBLK = BB * DD * BPP; // 12800 total blocks
constexpr int PER_XCD = NBLK / 8;   // 1600 blocks -> 32 contiguous planes per XCD

__device__ __forceinline__ int warp_index(int d, int h, int w,
                                          float f0, float f1, float f2) {
    // round-half-to-even (jnp.round == rintf), clamp per-dim
    int id = (int)fminf(fmaxf(rintf((float)d + f0), 0.0f), (float)(DD - 1));
    int ih = (int)fminf(fmaxf(rintf((float)h + f1), 0.0f), (float)(HH - 1));
    int iw = (int)fminf(fmaxf(rintf((float)w + f2), 0.0f), (float)(WW - 1));
    return (id * HH + ih) * WW + iw;
}

// One squaring step. IN_SOA: read [3,S] SoA (input x). OUT_SOA: write [3,S] SoA (d_out).
// Otherwise tight 12 B AoS [S,3]. 'scale' fuses the initial /64 on pass 1.
template <bool IN_SOA, bool OUT_SOA>
__global__ __launch_bounds__(256) void step_k(const float* __restrict__ vin,
                                              float* __restrict__ vout,
                                              float scale) {
    // XCD-aware swizzle: consecutive hardware block ids round-robin over 8 XCDs;
    // remap so each XCD owns a contiguous 1/8 slab (32 d-planes) of the volume.
    int bid = blockIdx.x;
    int nb  = (bid >> 3) + (bid & 7) * PER_XCD;
    int b   = nb / (DD * BPP);
    int r   = nb - b * (DD * BPP);
    int d   = r / BPP;
    int ip0 = (r - d * BPP) * VPB + threadIdx.x;   // voxel-in-plane, lane 0..255
    int ip1 = ip0 + 256;

    int w0 = ip0 % WW, h0 = ip0 / WW;
    int w1 = ip1 % WW, h1 = ip1 / WW;
    int p0 = d * PL + ip0;
    int p1 = d * PL + ip1;

    // --- center reads (both voxels first: MLP) ---
    float a0, a1, a2, c0, c1, c2;
    if constexpr (IN_SOA) {
        int s0 = b * 3 * S + p0, s1 = b * 3 * S + p1;
        a0 = vin[s0] * scale; a1 = vin[s0 + S] * scale; a2 = vin[s0 + 2 * S] * scale;
        c0 = vin[s1] * scale; c1 = vin[s1 + S] * scale; c2 = vin[s1 + 2 * S] * scale;
    } else {
        int i0 = (b * S + p0) * 3, i1 = (b * S + p1) * 3;
        a0 = vin[i0] * scale; a1 = vin[i0 + 1] * scale; a2 = vin[i0 + 2] * scale;
        c0 = vin[i1] * scale; c1 = vin[i1 + 1] * scale; c2 = vin[i1 + 2] * scale;
    }

    int q0 = warp_index(d, h0, w0, a0, a1, a2);
    int q1 = warp_index(d, h1, w1, c0, c1, c2);

    // --- gathers (two independent chains) ---
    float g0, g1, g2, e0, e1, e2;
    if constexpr (IN_SOA) {
        int s0 = b * 3 * S + q0, s1 = b * 3 * S + q1;
        g0 = vin[s0] * scale; g1 = vin[s0 + S] * scale; g2 = vin[s0 + 2 * S] * scale;
        e0 = vin[s1] * scale; e1 = vin[s1 + S] * scale; e2 = vin[s1 + 2 * S] * scale;
    } else {
        int i0 = (b * S + q0) * 3, i1 = (b * S + q1) * 3;
        g0 = vin[i0] * scale; g1 = vin[i0 + 1] * scale; g2 = vin[i0 + 2] * scale;
        e0 = vin[i1] * scale; e1 = vin[i1 + 1] * scale; e2 = vin[i1 + 2] * scale;
    }

    // --- stores ---
    if constexpr (OUT_SOA) {
        int s0 = b * 3 * S + p0, s1 = b * 3 * S + p1;
        vout[s0] = a0 + g0; vout[s0 + S] = a1 + g1; vout[s0 + 2 * S] = a2 + g2;
        vout[s1] = c0 + e0; vout[s1 + S] = c1 + e1; vout[s1 + 2 * S] = c2 + e2;
    } else {
        int i0 = (b * S + p0) * 3, i1 = (b * S + p1) * 3;
        vout[i0] = a0 + g0; vout[i0 + 1] = a1 + g1; vout[i0 + 2] = a2 + g2;
        vout[i1] = c0 + e0; vout[i1 + 1] = c1 + e1; vout[i1 + 2] = c2 + e2;
    }
}

extern "C" void kernel_launch(void* const* d_in, const int* in_sizes, int n_in,
                              void* d_out, int out_size, void* d_ws, size_t ws_size,
                              hipStream_t stream) {
    const float* x = (const float*)d_in[0];
    float* out = (float*)d_out;     // 78,643,200 bytes — doubles as AoS intermediate
    float* ws  = (float*)d_ws;      // needs >= 78,643,200 bytes (tight AoS)

    // 6 passes, ping-pong ws <-> out so pass 6 lands in out (SoA).
    step_k<true,  false><<<NBLK, 256, 0, stream>>>(x,   ws,  1.0f / 64.0f); // 1
    step_k<false, false><<<NBLK, 256, 0, stream>>>(ws,  out, 1.0f);         // 2
    step_k<false, false><<<NBLK, 256, 0, stream>>>(out, ws,  1.0f);         // 3
    step_k<false, false><<<NBLK, 256, 0, stream>>>(ws,  out, 1.0f);         // 4
    step_k<false, false><<<NBLK, 256, 0, stream>>>(out, ws,  1.0f);         // 5
    step_k<false, true ><<<NBLK, 256, 0, stream>>>(ws,  out, 1.0f);         // 6
}